// Round 15
// baseline (1060.425 us; speedup 1.0000x reference)
//
#include <hip/hip_runtime.h>
#include <math.h>

#define NN 1024
#define DD 64
#define HH 256
#define TEMP_INV 10.0f
#define KCH 64
#define NCH 4

typedef float v2f __attribute__((ext_vector_type(2)));

// ws layout (floats):
//   x2T [HH][NN] : xp + b1, k-major     1 MB
//   y2  [NN][HH] : yp, row-major        1 MB
//   pmax [16][NN], psum [16][NN], pos [NN]
//
// k1/k3 = R12 verbatim. k2 = R12 + (w2 via LDS -> pure-DS lgkmcnt, fine
// waits) + (y ping-pong register prefetch one 4-kk group ahead).

__global__ __launch_bounds__(256)
void k1_proj(const float* __restrict__ x, const float* __restrict__ y,
             const float* __restrict__ W1, const float* __restrict__ b1,
             float* __restrict__ x2T, float* __restrict__ y2)
{
    const int tid = threadIdx.x;        // h index 0..255
    const int i0 = blockIdx.x * 2;      // 2 rows per block -> 512 blocks
    float ax0 = 0.f, ax1 = 0.f, ay0 = 0.f, ay1 = 0.f;
    #pragma unroll 8
    for (int kk = 0; kk < DD; ++kk) {
        const float wx = W1[kk * HH + tid];
        const float wy = W1[(DD + kk) * HH + tid];
        ax0 = fmaf(x[i0 * DD + kk],       wx, ax0);
        ax1 = fmaf(x[(i0 + 1) * DD + kk], wx, ax1);
        ay0 = fmaf(y[i0 * DD + kk],       wy, ay0);
        ay1 = fmaf(y[(i0 + 1) * DD + kk], wy, ay1);
    }
    const float b1t = b1[tid];
    *(float2*)&x2T[tid * NN + i0] = make_float2(ax0 + b1t, ax1 + b1t);
    y2[i0 * HH + tid]       = ay0;      // coalesced over tid
    y2[(i0 + 1) * HH + tid] = ay1;
}

__global__ __launch_bounds__(256, 2)
void k2_scores(const float* __restrict__ x2T, const float* __restrict__ y2,
               const float* __restrict__ w2, const float* __restrict__ b2,
               float* __restrict__ pmax, float* __restrict__ psum,
               float* __restrict__ pos)
{
    __shared__ float xs[2][KCH][64];   // 32 KB, double-buffered
    __shared__ float w2s[HH];          // 1 KB
    const int t  = threadIdx.x;
    const int bj = blockIdx.x;         // 0..15 -> 64 cols
    const int bi = blockIdx.y;         // 0..31 -> 32 rows
    const int j0 = bj * 64;
    const int rr = t >> 5;             // 0..7
    const int cc = t & 31;             // 0..31
    const int rbase = bi * 32 + rr * 4;
    const float* yb = y2 + rbase * HH;

    const int wv  = t >> 6;            // wave id (wave-uniform)
    const int ln  = t & 63;
    const int sro = ln >> 4;           // 0..3
    const int sco = (ln & 15) * 4;

    w2s[t] = w2[t];                    // covered by first __syncthreads

    v2f acc[4];
    #pragma unroll
    for (int p = 0; p < 4; ++p) acc[p] = (v2f){0.f, 0.f};
    const v2f zero = {0.f, 0.f};

    #define STAGE(c, b)                                                        \
    {                                                                          \
        _Pragma("unroll")                                                      \
        for (int h = 0; h < 4; ++h) {                                          \
            const int row = wv * 16 + h * 4;                                   \
            const float* gsrc =                                               \
                &x2T[((c) * KCH + row + sro) * NN + j0 + sco];                 \
            __builtin_amdgcn_global_load_lds(                                  \
                (const __attribute__((address_space(1))) unsigned int*)gsrc,   \
                (__attribute__((address_space(3))) unsigned int*)&xs[b][row][0],\
                16, 0, 0);                                                     \
        }                                                                      \
    }

    // compute one 4-kk group G of chunk c, y regs in Y
    #define COMPUTE(G, Y)                                                      \
    {                                                                          \
        const float4 w4 = *(const float4*)&w2s[c * KCH + (G) * 4];             \
        _Pragma("unroll")                                                      \
        for (int e = 0; e < 4; ++e) {                                          \
            const float wk = (e == 0) ? w4.x : (e == 1) ? w4.y                 \
                           : (e == 2) ? w4.z : w4.w;                           \
            const v2f wv2 = {wk, wk};                                          \
            const v2f xv = *(const v2f*)&xs[cur][(G) * 4 + e][cc * 2];         \
            _Pragma("unroll")                                                  \
            for (int p = 0; p < 4; ++p) {                                      \
                const float yv = (e == 0) ? Y[p].x : (e == 1) ? Y[p].y         \
                               : (e == 2) ? Y[p].z : Y[p].w;                   \
                v2f z = xv + (v2f){yv, yv};             /* v_pk_add_f32 */     \
                z = __builtin_elementwise_max(z, zero); /* v_pk_max_f32 */     \
                acc[p] = z * wv2 + acc[p];              /* v_pk_fma_f32 */     \
            }                                                                  \
        }                                                                      \
    }

    STAGE(0, 0);

    float4 yA[4], yB[4];
    #pragma unroll
    for (int p = 0; p < 4; ++p) yA[p] = *(const float4*)&yb[p * HH];

    #pragma unroll
    for (int c = 0; c < NCH; ++c) {
        __syncthreads();               // drains stage(c); covers w2s on c==0
        if (c + 1 < NCH) STAGE(c + 1, (c + 1) & 1);
        const int cur = c & 1;
        #pragma unroll
        for (int gp = 0; gp < 8; ++gp) {
            {   // even group g = 2*gp: compute from yA, prefetch yB
                const int gg = c * 16 + gp * 2;
                #pragma unroll
                for (int p = 0; p < 4; ++p)
                    yB[p] = *(const float4*)&yb[p * HH + (gg + 1) * 4];
                COMPUTE(gp * 2, yA)
            }
            {   // odd group g = 2*gp+1: compute from yB, prefetch yA
                const int gg = c * 16 + gp * 2 + 1;
                if (gg + 1 < 64) {
                    #pragma unroll
                    for (int p = 0; p < 4; ++p)
                        yA[p] = *(const float4*)&yb[p * HH + (gg + 1) * 4];
                }
                COMPUTE(gp * 2 + 1, yB)
            }
        }
    }
    #undef STAGE
    #undef COMPUTE

    // epilogue: scores, diagonal -> pos, per-row partial LSE over 64 cols
    const float bb = b2[0];
    const v2f bbv = {bb, bb};
    v2f sc[4];
    #pragma unroll
    for (int p = 0; p < 4; ++p) sc[p] = (acc[p] + bbv) * TEMP_INV;

    const int col0 = j0 + cc * 2;
    #pragma unroll
    for (int p = 0; p < 4; ++p) {
        const int row = rbase + p;
        if (row == col0)     pos[row] = sc[p].x;
        if (row == col0 + 1) pos[row] = sc[p].y;
    }

    float m[4], e[4];
    #pragma unroll
    for (int p = 0; p < 4; ++p) {
        m[p] = fmaxf(sc[p].x, sc[p].y);
        e[p] = __expf(sc[p].x - m[p]) + __expf(sc[p].y - m[p]);
    }
    #pragma unroll
    for (int mk = 16; mk >= 1; mk >>= 1) {
        #pragma unroll
        for (int p = 0; p < 4; ++p) {
            const float mo = __shfl_xor(m[p], mk);
            const float eo = __shfl_xor(e[p], mk);
            const float mn = fmaxf(m[p], mo);
            e[p] = e[p] * __expf(m[p] - mn) + eo * __expf(mo - mn);
            m[p] = mn;
        }
    }
    if (cc == 0) {
        #pragma unroll
        for (int p = 0; p < 4; ++p) {
            pmax[bj * NN + rbase + p] = m[p];
            psum[bj * NN + rbase + p] = e[p];
        }
    }
}

__global__ __launch_bounds__(1024)
void k3_final(const float* __restrict__ pmax, const float* __restrict__ psum,
              const float* __restrict__ pos, float* __restrict__ out)
{
    __shared__ float2 red[1024];
    const int tid = threadIdx.x;      // row
    float M = pmax[tid], E = psum[tid];
    #pragma unroll
    for (int jc = 1; jc < 16; ++jc) {
        const float Mo = pmax[jc * NN + tid];
        const float Eo = psum[jc * NN + tid];
        const float Mn = fmaxf(M, Mo);
        E = E * __expf(M - Mn) + Eo * __expf(Mo - Mn);
        M = Mn;
    }
    red[tid] = make_float2(M + logf(E), pos[tid]);
    __syncthreads();
    for (int s = 512; s > 0; s >>= 1) {
        if (tid < s) {
            const float2 o = red[tid + s];
            float2 m2 = red[tid];
            m2.x += o.x; m2.y += o.y;
            red[tid] = m2;
        }
        __syncthreads();
    }
    if (tid == 0)
        out[0] = red[0].x / (float)NN - logf((float)NN) - red[0].y / (float)NN;
}

extern "C" void kernel_launch(void* const* d_in, const int* in_sizes, int n_in,
                              void* d_out, int out_size, void* d_ws, size_t ws_size,
                              hipStream_t stream)
{
    const float* x  = (const float*)d_in[0];
    const float* y  = (const float*)d_in[1];
    const float* W1 = (const float*)d_in[2];
    const float* b1 = (const float*)d_in[3];
    const float* w2 = (const float*)d_in[4];
    const float* b2 = (const float*)d_in[5];
    float* out = (float*)d_out;

    float* ws   = (float*)d_ws;
    float* x2T  = ws;                 // 256*1024
    float* y2   = x2T + HH * NN;      // 1024*256
    float* pmax = y2 + NN * HH;       // 16*1024
    float* psum = pmax + 16 * NN;     // 16*1024
    float* pos  = psum + 16 * NN;     // 1024

    hipLaunchKernelGGL(k1_proj, dim3(NN / 2), dim3(256), 0, stream,
                       x, y, W1, b1, x2T, y2);
    hipLaunchKernelGGL(k2_scores, dim3(16, 32), dim3(256), 0, stream,
                       x2T, y2, w2, b2, pmax, psum, pos);
    hipLaunchKernelGGL(k3_final, dim3(1), dim3(1024), 0, stream,
                       pmax, psum, pos, out);
}

// Round 16
// 41.022 us; speedup vs baseline: 25.8500x; 25.8500x over previous
//
#include <hip/hip_runtime.h>
#include <math.h>

#define NN 1024
#define DD 64
#define HH 256
#define TEMP_INV 10.0f
#define KCH 64
#define NCH 4
#define NBLK2 512u

typedef float v2f __attribute__((ext_vector_type(2)));

// ws layout (floats):
//   x2T [HH][NN] : xp + b1, k-major     1 MB
//   y2  [NN][HH] : yp, row-major        1 MB
//   E   [NN]     : per-row sum(exp(score)) (fixed max = 0)
//   gacc[2]      : [0] unused, [1] sum of diagonal scores
//   tick (u32)
//
// 2 kernels, 1 gap. k2 compute = R12 verbatim; epilogue = fixed-max exp-sum
// + device-scope atomic fan-in + ticket finalize (no fences, no spins).

__global__ __launch_bounds__(256)
void k1_proj(const float* __restrict__ x, const float* __restrict__ y,
             const float* __restrict__ W1, const float* __restrict__ b1,
             float* __restrict__ x2T, float* __restrict__ y2,
             float* __restrict__ E, float* __restrict__ gacc,
             unsigned int* __restrict__ tick)
{
    const int tid = threadIdx.x;        // h index 0..255
    if (blockIdx.x == 0) {              // re-arm accumulators every call
        *(float4*)&E[tid * 4] = make_float4(0.f, 0.f, 0.f, 0.f);
        if (tid == 0) { gacc[0] = 0.f; gacc[1] = 0.f; tick[0] = 0u; }
    }
    const int i0 = blockIdx.x * 2;      // 2 rows per block -> 512 blocks
    float ax0 = 0.f, ax1 = 0.f, ay0 = 0.f, ay1 = 0.f;
    #pragma unroll 8
    for (int kk = 0; kk < DD; ++kk) {
        const float wx = W1[kk * HH + tid];
        const float wy = W1[(DD + kk) * HH + tid];
        ax0 = fmaf(x[i0 * DD + kk],       wx, ax0);
        ax1 = fmaf(x[(i0 + 1) * DD + kk], wx, ax1);
        ay0 = fmaf(y[i0 * DD + kk],       wy, ay0);
        ay1 = fmaf(y[(i0 + 1) * DD + kk], wy, ay1);
    }
    const float b1t = b1[tid];
    *(float2*)&x2T[tid * NN + i0] = make_float2(ax0 + b1t, ax1 + b1t);
    y2[i0 * HH + tid]       = ay0;      // coalesced over tid
    y2[(i0 + 1) * HH + tid] = ay1;
}

__global__ __launch_bounds__(256, 2)
void k2_scores(const float* __restrict__ x2T, const float* __restrict__ y2,
               const float* __restrict__ w2, const float* __restrict__ b2,
               float* __restrict__ E, float* __restrict__ gacc,
               unsigned int* __restrict__ tick, float* __restrict__ out)
{
    __shared__ float xs[2][KCH][64];   // 32 KB, double-buffered
    __shared__ float redf[256];
    __shared__ unsigned int s_old;
    const int t  = threadIdx.x;
    const int bj = blockIdx.x;         // 0..15 -> 64 cols
    const int bi = blockIdx.y;         // 0..31 -> 32 rows
    const int j0 = bj * 64;
    const int rr = t >> 5;             // 0..7
    const int cc = t & 31;             // 0..31
    const int rbase = bi * 32 + rr * 4;
    const float* yb = y2 + rbase * HH;

    const int wv  = t >> 6;            // wave id (wave-uniform)
    const int ln  = t & 63;
    const int sro = ln >> 4;           // 0..3
    const int sco = (ln & 15) * 4;

    v2f acc[4];
    #pragma unroll
    for (int p = 0; p < 4; ++p) acc[p] = (v2f){0.f, 0.f};
    const v2f zero = {0.f, 0.f};

    #define STAGE(c, b)                                                        \
    {                                                                          \
        _Pragma("unroll")                                                      \
        for (int h = 0; h < 4; ++h) {                                          \
            const int row = wv * 16 + h * 4;                                   \
            const float* gsrc =                                               \
                &x2T[((c) * KCH + row + sro) * NN + j0 + sco];                 \
            __builtin_amdgcn_global_load_lds(                                  \
                (const __attribute__((address_space(1))) unsigned int*)gsrc,   \
                (__attribute__((address_space(3))) unsigned int*)&xs[b][row][0],\
                16, 0, 0);                                                     \
        }                                                                      \
    }

    STAGE(0, 0);
    for (int c = 0; c < NCH; ++c) {
        __syncthreads();
        if (c + 1 < NCH) STAGE(c + 1, (c + 1) & 1);
        const int cur = c & 1;
        #pragma unroll
        for (int g = 0; g < 16; ++g) {
            const int gg = c * 16 + g;
            float4 yv4[4];
            #pragma unroll
            for (int p = 0; p < 4; ++p)
                yv4[p] = *(const float4*)&yb[p * HH + gg * 4];
            #pragma unroll
            for (int e = 0; e < 4; ++e) {
                const float wk = w2[gg * 4 + e];      // uniform -> s_load
                const v2f wv2 = {wk, wk};
                const v2f xv = *(const v2f*)&xs[cur][g * 4 + e][cc * 2];
                #pragma unroll
                for (int p = 0; p < 4; ++p) {
                    const float yv = (e == 0) ? yv4[p].x : (e == 1) ? yv4[p].y
                                   : (e == 2) ? yv4[p].z : yv4[p].w;
                    v2f z = xv + (v2f){yv, yv};             // v_pk_add_f32
                    z = __builtin_elementwise_max(z, zero); // v_pk_max_f32
                    acc[p] = z * wv2 + acc[p];              // v_pk_fma_f32
                }
            }
        }
    }
    #undef STAGE

    // ---- epilogue: fixed-max (M0=0) exp-sums + atomic fan-in ----
    const float bb = b2[0];
    const v2f bbv = {bb, bb};
    v2f sc[4];
    #pragma unroll
    for (int p = 0; p < 4; ++p) sc[p] = (acc[p] + bbv) * TEMP_INV;

    // diagonal contribution (a thread can own both of its 2 cols' diagonals)
    const int col0 = j0 + cc * 2;
    float dv = 0.f; bool isd = false;
    #pragma unroll
    for (int p = 0; p < 4; ++p) {
        const int row = rbase + p;
        if (row == col0)     { dv += sc[p].x; isd = true; }
        if (row == col0 + 1) { dv += sc[p].y; isd = true; }
    }
    if (isd) atomicAdd(&gacc[1], dv);

    float e_[4];
    #pragma unroll
    for (int p = 0; p < 4; ++p)
        e_[p] = __expf(sc[p].x) + __expf(sc[p].y);
    #pragma unroll
    for (int mk = 16; mk >= 1; mk >>= 1) {
        #pragma unroll
        for (int p = 0; p < 4; ++p)
            e_[p] += __shfl_xor(e_[p], mk);
    }
    if (cc == 0) {
        #pragma unroll
        for (int p = 0; p < 4; ++p)
            atomicAdd(&E[rbase + p], e_[p]);
    }

    // ---- ticket fan-in: last block finalizes (no fences, no spin) ----
    asm volatile("s_waitcnt vmcnt(0)" ::: "memory");  // this wave's atomics done
    __syncthreads();
    if (t == 0) s_old = atomicAdd(tick, 1u);
    __syncthreads();
    if (s_old == NBLK2 - 1u) {
        float ls = 0.f;
        #pragma unroll
        for (int r = 0; r < 4; ++r) {
            const float ev = __hip_atomic_load(&E[t + r * 256],
                                               __ATOMIC_RELAXED,
                                               __HIP_MEMORY_SCOPE_AGENT);
            ls += logf(ev);
        }
        redf[t] = ls;
        __syncthreads();
        for (int s2 = 128; s2 > 0; s2 >>= 1) {
            if (t < s2) redf[t] += redf[t + s2];
            __syncthreads();
        }
        if (t == 0) {
            const float pos_sum = __hip_atomic_load(&gacc[1], __ATOMIC_RELAXED,
                                                    __HIP_MEMORY_SCOPE_AGENT);
            out[0] = redf[0] / (float)NN - logf((float)NN)
                   - pos_sum / (float)NN;
        }
    }
}

extern "C" void kernel_launch(void* const* d_in, const int* in_sizes, int n_in,
                              void* d_out, int out_size, void* d_ws, size_t ws_size,
                              hipStream_t stream)
{
    const float* x  = (const float*)d_in[0];
    const float* y  = (const float*)d_in[1];
    const float* W1 = (const float*)d_in[2];
    const float* b1 = (const float*)d_in[3];
    const float* w2 = (const float*)d_in[4];
    const float* b2 = (const float*)d_in[5];
    float* out = (float*)d_out;

    float* ws   = (float*)d_ws;
    float* x2T  = ws;                 // 256*1024
    float* y2   = x2T + HH * NN;      // 1024*256
    float* E    = y2 + NN * HH;       // 1024
    float* gacc = E + NN;             // 2
    unsigned int* tick = (unsigned int*)(gacc + 2);

    hipLaunchKernelGGL(k1_proj, dim3(NN / 2), dim3(256), 0, stream,
                       x, y, W1, b1, x2T, y2, E, gacc, tick);
    hipLaunchKernelGGL(k2_scores, dim3(16, 32), dim3(256), 0, stream,
                       x2T, y2, w2, b2, E, gacc, tick, out);
}

// Round 17
// 39.933 us; speedup vs baseline: 26.5551x; 1.0273x over previous
//
#include <hip/hip_runtime.h>
#include <math.h>

#define NN 1024
#define DD 64
#define HH 256
#define TEMP_INV 10.0f
#define KCH 64
#define NCH 4
#define NBLK2 256u

typedef float v2f __attribute__((ext_vector_type(2)));

// ws layout (floats):
//   x2T [HH][NN] : xp + b1, k-major     1 MB
//   y2  [NN][HH] : yp, row-major        1 MB
//   E   [NN]     : per-row sum(exp(score)) (fixed max = 0)
//   gacc[2], tick (u32)
//
// R16 structure, occupancy x2: 512-thr blocks, 64x64 tile, grid 16x16,
// 2 blocks/CU -> 4 waves/SIMD (was 2). Compute per thread identical (4x2).

__global__ __launch_bounds__(256)
void k1_proj(const float* __restrict__ x, const float* __restrict__ y,
             const float* __restrict__ W1, const float* __restrict__ b1,
             float* __restrict__ x2T, float* __restrict__ y2,
             float* __restrict__ E, float* __restrict__ gacc,
             unsigned int* __restrict__ tick)
{
    const int tid = threadIdx.x;        // h index 0..255
    if (blockIdx.x == 0) {              // re-arm accumulators every call
        *(float4*)&E[tid * 4] = make_float4(0.f, 0.f, 0.f, 0.f);
        if (tid == 0) { gacc[0] = 0.f; gacc[1] = 0.f; tick[0] = 0u; }
    }
    const int i0 = blockIdx.x * 2;      // 2 rows per block -> 512 blocks
    float ax0 = 0.f, ax1 = 0.f, ay0 = 0.f, ay1 = 0.f;
    #pragma unroll 8
    for (int kk = 0; kk < DD; ++kk) {
        const float wx = W1[kk * HH + tid];
        const float wy = W1[(DD + kk) * HH + tid];
        ax0 = fmaf(x[i0 * DD + kk],       wx, ax0);
        ax1 = fmaf(x[(i0 + 1) * DD + kk], wx, ax1);
        ay0 = fmaf(y[i0 * DD + kk],       wy, ay0);
        ay1 = fmaf(y[(i0 + 1) * DD + kk], wy, ay1);
    }
    const float b1t = b1[tid];
    *(float2*)&x2T[tid * NN + i0] = make_float2(ax0 + b1t, ax1 + b1t);
    y2[i0 * HH + tid]       = ay0;      // coalesced over tid
    y2[(i0 + 1) * HH + tid] = ay1;
}

__global__ __launch_bounds__(512, 4)
void k2_scores(const float* __restrict__ x2T, const float* __restrict__ y2,
               const float* __restrict__ w2, const float* __restrict__ b2,
               float* __restrict__ E, float* __restrict__ gacc,
               unsigned int* __restrict__ tick, float* __restrict__ out)
{
    __shared__ float xs[2][KCH][64];   // 32 KB, double-buffered
    __shared__ float redf[256];
    __shared__ unsigned int s_old;
    const int t  = threadIdx.x;        // 0..511
    const int bj = blockIdx.x;         // 0..15 -> 64 cols
    const int bi = blockIdx.y;         // 0..15 -> 64 rows
    const int j0 = bj * 64;
    const int rr = t >> 5;             // 0..15
    const int cc = t & 31;             // 0..31
    const int rbase = bi * 64 + rr * 4;
    const float* yb = y2 + rbase * HH;

    const int wv  = t >> 6;            // wave id 0..7 (wave-uniform)
    const int ln  = t & 63;
    const int sro = ln >> 4;           // 0..3
    const int sco = (ln & 15) * 4;

    v2f acc[4];
    #pragma unroll
    for (int p = 0; p < 4; ++p) acc[p] = (v2f){0.f, 0.f};
    const v2f zero = {0.f, 0.f};

    // stage chunk c into buffer b: 8 waves x 2 calls x (64 lanes*16B = 4 rows)
    #define STAGE(c, b)                                                        \
    {                                                                          \
        _Pragma("unroll")                                                      \
        for (int h = 0; h < 2; ++h) {                                          \
            const int row = wv * 8 + h * 4;                                    \
            const float* gsrc =                                               \
                &x2T[((c) * KCH + row + sro) * NN + j0 + sco];                 \
            __builtin_amdgcn_global_load_lds(                                  \
                (const __attribute__((address_space(1))) unsigned int*)gsrc,   \
                (__attribute__((address_space(3))) unsigned int*)&xs[b][row][0],\
                16, 0, 0);                                                     \
        }                                                                      \
    }

    STAGE(0, 0);
    for (int c = 0; c < NCH; ++c) {
        __syncthreads();
        if (c + 1 < NCH) STAGE(c + 1, (c + 1) & 1);
        const int cur = c & 1;
        #pragma unroll
        for (int g = 0; g < 16; ++g) {
            const int gg = c * 16 + g;
            float4 yv4[4];
            #pragma unroll
            for (int p = 0; p < 4; ++p)
                yv4[p] = *(const float4*)&yb[p * HH + gg * 4];
            #pragma unroll
            for (int e = 0; e < 4; ++e) {
                const float wk = w2[gg * 4 + e];      // uniform -> s_load
                const v2f wv2 = {wk, wk};
                const v2f xv = *(const v2f*)&xs[cur][g * 4 + e][cc * 2];
                #pragma unroll
                for (int p = 0; p < 4; ++p) {
                    const float yv = (e == 0) ? yv4[p].x : (e == 1) ? yv4[p].y
                                   : (e == 2) ? yv4[p].z : yv4[p].w;
                    v2f z = xv + (v2f){yv, yv};             // v_pk_add_f32
                    z = __builtin_elementwise_max(z, zero); // v_pk_max_f32
                    acc[p] = z * wv2 + acc[p];              // v_pk_fma_f32
                }
            }
        }
    }
    #undef STAGE

    // ---- epilogue: fixed-max (M0=0) exp-sums + atomic fan-in ----
    const float bb = b2[0];
    const v2f bbv = {bb, bb};
    v2f sc[4];
    #pragma unroll
    for (int p = 0; p < 4; ++p) sc[p] = (acc[p] + bbv) * TEMP_INV;

    const int col0 = j0 + cc * 2;
    float dv = 0.f; bool isd = false;
    #pragma unroll
    for (int p = 0; p < 4; ++p) {
        const int row = rbase + p;
        if (row == col0)     { dv += sc[p].x; isd = true; }
        if (row == col0 + 1) { dv += sc[p].y; isd = true; }
    }
    if (isd) atomicAdd(&gacc[1], dv);

    float e_[4];
    #pragma unroll
    for (int p = 0; p < 4; ++p)
        e_[p] = __expf(sc[p].x) + __expf(sc[p].y);
    #pragma unroll
    for (int mk = 16; mk >= 1; mk >>= 1) {   // reduce over cc (half-wave)
        #pragma unroll
        for (int p = 0; p < 4; ++p)
            e_[p] += __shfl_xor(e_[p], mk);
    }
    if (cc == 0) {
        #pragma unroll
        for (int p = 0; p < 4; ++p)
            atomicAdd(&E[rbase + p], e_[p]);
    }

    // ---- ticket fan-in: last block finalizes (no fences, no spin) ----
    asm volatile("s_waitcnt vmcnt(0)" ::: "memory");
    __syncthreads();
    if (t == 0) s_old = atomicAdd(tick, 1u);
    __syncthreads();
    if (s_old == NBLK2 - 1u) {
        if (t < 256) {
            float ls = 0.f;
            #pragma unroll
            for (int r = 0; r < 4; ++r) {
                const float ev = __hip_atomic_load(&E[t + r * 256],
                                                   __ATOMIC_RELAXED,
                                                   __HIP_MEMORY_SCOPE_AGENT);
                ls += logf(ev);
            }
            redf[t] = ls;
        }
        __syncthreads();
        for (int s2 = 128; s2 > 0; s2 >>= 1) {
            if (t < s2) redf[t] += redf[t + s2];
            __syncthreads();
        }
        if (t == 0) {
            const float pos_sum = __hip_atomic_load(&gacc[1], __ATOMIC_RELAXED,
                                                    __HIP_MEMORY_SCOPE_AGENT);
            out[0] = redf[0] / (float)NN - logf((float)NN)
                   - pos_sum / (float)NN;
        }
    }
}

extern "C" void kernel_launch(void* const* d_in, const int* in_sizes, int n_in,
                              void* d_out, int out_size, void* d_ws, size_t ws_size,
                              hipStream_t stream)
{
    const float* x  = (const float*)d_in[0];
    const float* y  = (const float*)d_in[1];
    const float* W1 = (const float*)d_in[2];
    const float* b1 = (const float*)d_in[3];
    const float* w2 = (const float*)d_in[4];
    const float* b2 = (const float*)d_in[5];
    float* out = (float*)d_out;

    float* ws   = (float*)d_ws;
    float* x2T  = ws;                 // 256*1024
    float* y2   = x2T + HH * NN;      // 1024*256
    float* E    = y2 + NN * HH;       // 1024
    float* gacc = E + NN;             // 2
    unsigned int* tick = (unsigned int*)(gacc + 2);

    hipLaunchKernelGGL(k1_proj, dim3(NN / 2), dim3(256), 0, stream,
                       x, y, W1, b1, x2T, y2, E, gacc, tick);
    hipLaunchKernelGGL(k2_scores, dim3(16, 16), dim3(512), 0, stream,
                       x2T, y2, w2, b2, E, gacc, tick, out);
}